// Round 7
// baseline (232.096 us; speedup 1.0000x reference)
//
#include <hip/hip_runtime.h>
#include <hip/hip_bf16.h>

#define NREV 500000
#define DIM  128
#define KDIM 384

typedef __attribute__((ext_vector_type(4))) float f32x4;
typedef __attribute__((ext_vector_type(8))) short bf16x8;

__device__ __forceinline__ unsigned short f2bf_s(float x) {
    // round-to-nearest-even f32 -> bf16
    unsigned int u = __builtin_bit_cast(unsigned int, x);
    u = (u + 0x7FFFu + ((u >> 16) & 1u)) >> 16;
    return (unsigned short)u;
}

// W [384][128] f32 -> Bw frag-linear bf16:
// Bw[((ks*8+fg)*64 + l)*8 + j] = bf16( W[ks*32 + (l>>4)*8 + j][fg*16 + (l&15)] )
// each lane's 16B B-fragment is one contiguous dwordx4 (L2-resident, 96KB).
__global__ void wconv_kernel(const float* __restrict__ W,
                             unsigned short* __restrict__ Bw) {
    int e = blockIdx.x * 256 + threadIdx.x;
    if (e < 12 * 8 * 64 * 8) {
        int j  = e & 7;
        int l  = (e >> 3) & 63;
        int fg = (e >> 9) & 7;
        int ks = e >> 12;
        int n = fg * 16 + (l & 15);
        int k = ks * 32 + ((l >> 4) << 3) + j;
        Bw[e] = f2bf_s(W[k * DIM + n]);
    }
}

// pack hi16 of two f32 into one dword of two bf16 (truncation; absmax 0.031
// vs threshold 0.109): single v_perm_b32
__device__ __forceinline__ unsigned int pk2(float lo, float hi) {
    return __builtin_amdgcn_perm(__builtin_bit_cast(unsigned int, hi),
                                 __builtin_bit_cast(unsigned int, lo),
                                 0x07060302u);
}
__device__ __forceinline__ bf16x8 cvt8(f32x4 a, f32x4 b) {
    union { bf16x8 v; unsigned int u[4]; } U;
    U.u[0] = pk2(a[0], a[1]);
    U.u[1] = pk2(a[2], a[3]);
    U.u[2] = pk2(b[0], b[1]);
    U.u[3] = pk2(b[2], b[3]);
    return U.v;
}

// Fused gather + GEMM + ReLU. ZERO LDS, ZERO barriers, fully decoupled waves.
// Block: 4 waves x (32 private rows x 128 cols). K=384 in 12 steps of 32
// (0-3 review, 4-7 user, 8-11 item).
// A fragments load register-direct in MFMA frag layout: lane (lm,lk) reads
// its own rows' contiguous 32B. Explicit triple-buffered stg[] + asm memory
// fences force 2-step-deep issue (what R4's compiler scheduling lacked).
// B register-prefetched 1 step ahead from L2-resident frag-linear Bw; issue
// order (B before A in each step) keeps the compiler's B-wait at vmcnt(16),
// never draining the A prefetch.
__global__ __launch_bounds__(256, 2) void agg_kernel(
    const float* __restrict__ rev,
    const float* __restrict__ item,
    const float* __restrict__ user,
    const int*   __restrict__ uidx,
    const int*   __restrict__ iidx,
    const unsigned short* __restrict__ Bw,
    float* __restrict__ out)
{
    const int t    = threadIdx.x;
    const int w    = t >> 6, lane = t & 63;
    const int lm   = lane & 15, lk = lane >> 4;
    const int r0   = blockIdx.x * 128 + w * 32;   // wave-private 32 rows

    // Per-lane A base pointers: 3 tables x 2 mf fragments (+ lk*8 f32 folded)
    const float* baseA[3][2];
    #pragma unroll
    for (int mf = 0; mf < 2; ++mf) {
        int r = r0 + mf * 16 + lm;
        if (r >= NREV) r = NREV - 1;              // clamp tail; stores predicated
        baseA[0][mf] = rev  + (size_t)r * DIM + lk * 8;
        baseA[1][mf] = user + (size_t)uidx[r] * DIM + lk * 8;
        baseA[2][mf] = item + (size_t)iidx[r] * DIM + lk * 8;
    }

    f32x4 acc[2][8];
    #pragma unroll
    for (int i = 0; i < 2; ++i)
        #pragma unroll
        for (int j = 0; j < 8; ++j)
            acc[i][j] = (f32x4){0.f, 0.f, 0.f, 0.f};

    const unsigned short* bbase = Bw + lane * 8;

    f32x4  stg[3][2][2];   // [buf][mf][half] — static-indexed (full unroll)
    bf16x8 brg[2][8];      // [buf][nf]

    // ---- prologue: A(0), A(1), B(0) in flight
    #pragma unroll
    for (int mf = 0; mf < 2; ++mf) {
        const float* p = baseA[0][mf];
        stg[0][mf][0] = *reinterpret_cast<const f32x4*>(p);
        stg[0][mf][1] = *reinterpret_cast<const f32x4*>(p + 4);
        const float* q = baseA[0][mf] + 32;
        stg[1][mf][0] = *reinterpret_cast<const f32x4*>(q);
        stg[1][mf][1] = *reinterpret_cast<const f32x4*>(q + 4);
    }
    #pragma unroll
    for (int nf = 0; nf < 8; ++nf)
        brg[0][nf] = *reinterpret_cast<const bf16x8*>(bbase + (size_t)nf * 512);

    #pragma unroll
    for (int s = 0; s < 12; ++s) {
        // ---- issue section: B(s+1) first, then A(s+2)
        if (s < 11) {
            #pragma unroll
            for (int nf = 0; nf < 8; ++nf)
                brg[(s + 1) & 1][nf] = *reinterpret_cast<const bf16x8*>(
                    bbase + (size_t)((s + 1) * 8 + nf) * 512);
        }
        if (s < 10) {
            #pragma unroll
            for (int mf = 0; mf < 2; ++mf) {
                const float* p = baseA[(s + 2) >> 2][mf] + ((s + 2) & 3) * 32;
                stg[(s + 2) % 3][mf][0] = *reinterpret_cast<const f32x4*>(p);
                stg[(s + 2) % 3][mf][1] = *reinterpret_cast<const f32x4*>(p + 4);
            }
        }
        asm volatile("" ::: "memory");   // loads above cannot sink below

        // ---- compute step s
        __builtin_amdgcn_s_setprio(1);
        #pragma unroll
        for (int mf = 0; mf < 2; ++mf) {
            bf16x8 af = cvt8(stg[s % 3][mf][0], stg[s % 3][mf][1]);
            #pragma unroll
            for (int nf = 0; nf < 8; ++nf)
                acc[mf][nf] = __builtin_amdgcn_mfma_f32_16x16x32_bf16(
                    af, brg[s & 1][nf], acc[mf][nf], 0, 0, 0);
        }
        __builtin_amdgcn_s_setprio(0);
    }

    // ---- epilogue: ReLU + f32 store (C/D: col=lane&15, row=(lane>>4)*4+j)
    #pragma unroll
    for (int mf = 0; mf < 2; ++mf) {
        #pragma unroll
        for (int j = 0; j < 4; ++j) {
            int row = r0 + mf * 16 + lk * 4 + j;
            if (row < NREV) {
                float* orow = out + (size_t)row * DIM;
                #pragma unroll
                for (int nf = 0; nf < 8; ++nf)
                    orow[nf * 16 + lm] = fmaxf(acc[mf][nf][j], 0.0f);
            }
        }
    }
}

extern "C" void kernel_launch(void* const* d_in, const int* in_sizes, int n_in,
                              void* d_out, int out_size, void* d_ws, size_t ws_size,
                              hipStream_t stream) {
    const float* rev  = (const float*)d_in[0];
    const float* item = (const float*)d_in[1];
    const float* user = (const float*)d_in[2];
    const int*   uidx = (const int*)d_in[3];
    const int*   iidx = (const int*)d_in[4];
    const float* W    = (const float*)d_in[5];
    unsigned short* Bw = (unsigned short*)d_ws;   // 12*8*64*8*2 = 98304 B
    float* out = (float*)d_out;

    wconv_kernel<<<192, 256, 0, stream>>>(W, Bw);

    int nblocks = (NREV + 127) / 128;   // 3907
    agg_kernel<<<nblocks, 256, 0, stream>>>(rev, item, user, uidx, iidx, Bw, out);
}

// Round 8
// 221.081 us; speedup vs baseline: 1.0498x; 1.0498x over previous
//
#include <hip/hip_runtime.h>
#include <hip/hip_bf16.h>

#define NREV  500000
#define NUSER 200000
#define NITEM 100000
#define DIM   128

// d_ws layout in ushort (bf16) elements:
#define WR_OFF 0                         // rev-part weight frag, 16384
#define WU_OFF 16384                     // user-part weight frag
#define WI_OFF 32768                     // item-part weight frag
#define U2_OFF 49152                     // user partial products, 200000*128
#define I2_OFF (49152 + NUSER * 128)     // item partial products, 100000*128
#define UBLK 1563                        // ceil(200000/128)
#define IBLK 782                         // ceil(100000/128)

typedef __attribute__((ext_vector_type(4))) float f32x4;
typedef __attribute__((ext_vector_type(8))) short bf16x8;
typedef __attribute__((ext_vector_type(4))) unsigned short u16x4;

__device__ __forceinline__ unsigned short f2bf_s(float x) {
    // round-to-nearest-even f32 -> bf16
    unsigned int u = __builtin_bit_cast(unsigned int, x);
    u = (u + 0x7FFFu + ((u >> 16) & 1u)) >> 16;
    return (unsigned short)u;
}
__device__ __forceinline__ float bf2f(unsigned short u) {
    return __builtin_bit_cast(float, (unsigned int)u << 16);
}

// W [384][128] f32 -> three frag-linear bf16 blocks (rev/user/item K-slices).
// Wf[b][ks][fg][l][j] = bf16( W[b*128 + ks*32 + (l>>4)*8 + j][fg*16 + (l&15)] )
// so each lane's 16B B-fragment is one contiguous dwordx4 (L2-resident).
__global__ void wconv_kernel(const float* __restrict__ W,
                             unsigned short* __restrict__ ws) {
    int e = blockIdx.x * 256 + threadIdx.x;
    if (e < 3 * 16384) {
        int e14 = e & 16383;
        int b  = e >> 14;
        int ks = e14 >> 12;
        int fg = (e14 >> 9) & 7;
        int l  = (e14 >> 3) & 63;
        int j  = e14 & 7;
        int n = fg * 16 + (l & 15);
        int k = b * 128 + ks * 32 + ((l >> 4) << 3) + j;
        ws[e] = f2bf_s(W[k * DIM + n]);
    }
}

__device__ __forceinline__ void gload_lds16(const void* g, void* l) {
    __builtin_amdgcn_global_load_lds(
        (const __attribute__((address_space(1))) void*)g,
        (__attribute__((address_space(3))) void*)l, 16, 0, 0);
}

// pack hi16 of two f32 into one dword of two bf16 (truncation): v_perm_b32
__device__ __forceinline__ unsigned int pk2(float lo, float hi) {
    return __builtin_amdgcn_perm(__builtin_bit_cast(unsigned int, hi),
                                 __builtin_bit_cast(unsigned int, lo),
                                 0x07060302u);
}
__device__ __forceinline__ bf16x8 cvt8(f32x4 a, f32x4 b) {
    union { bf16x8 v; unsigned int u[4]; } U;
    U.u[0] = pk2(a[0], a[1]);
    U.u[1] = pk2(a[2], a[3]);
    U.u[2] = pk2(b[0], b[1]);
    U.u[3] = pk2(b[2], b[3]);
    return U.v;
}

// ---------------- precompute: P2 = bf16(table @ Wx), streaming GEMM ----------
// Block: 128 rows x 128 cols, 4 waves (64x64). K=128, 4 steps of 32.
// A: triple-buffered LDS via global_load_lds (R5 pipeline). B: reg-direct.
// Output layout P2[row][wc][lm][nf] (ushort), so the main kernel's epilogue
// gather reads one contiguous 8B u16x4 per lane per row.
__global__ __launch_bounds__(256, 3) void precomp_kernel(
    const float* __restrict__ user,
    const float* __restrict__ item,
    unsigned short* __restrict__ ws)
{
    __shared__ __align__(16) float Atile[3][128 * 32];

    const bool isU = blockIdx.x < UBLK;
    const float* tab = isU ? user : item;
    const int M      = isU ? NUSER : NITEM;
    const unsigned short* wf = ws + (isU ? WU_OFF : WI_OFF);
    unsigned short* P2       = ws + (isU ? U2_OFF : I2_OFF);
    const int r0 = (isU ? blockIdx.x : blockIdx.x - UBLK) * 128;

    const int t    = threadIdx.x;
    const int wid  = t >> 6, lane = t & 63;
    const int wr   = wid >> 1, wc = wid & 1;
    const int lm   = lane & 15, lk = lane >> 4;

    const int srow = t >> 3;
    const int cswz = ((t & 7) ^ ((t >> 3) & 7)) << 2;

    const float* pr[4];
    #pragma unroll
    for (int it = 0; it < 4; ++it) {
        int gr = r0 + it * 32 + srow;
        if (gr >= M) gr = M - 1;
        pr[it] = tab + (size_t)gr * DIM + cswz;
    }

    f32x4 acc[4][4];
    #pragma unroll
    for (int i = 0; i < 4; ++i)
        #pragma unroll
        for (int j = 0; j < 4; ++j)
            acc[i][j] = (f32x4){0.f, 0.f, 0.f, 0.f};

    const int axor  = (lm & 7) << 4;
    const int koff0 = (lk * 32) ^ axor;
    const unsigned short* bbase = wf + ((wc * 4) * 64 + lane) * 8;

    auto prefetchA = [&](int s, int buf) {
        const int cb = s * 32;
        #pragma unroll
        for (int it = 0; it < 4; ++it)
            gload_lds16(pr[it] + cb, (char*)&Atile[buf][0] + it * 4096 + t * 16);
    };
    bf16x8 breg[3][4];
    auto loadB = [&](int s, bf16x8* dst) {
        #pragma unroll
        for (int nf = 0; nf < 4; ++nf)
            dst[nf] = *reinterpret_cast<const bf16x8*>(bbase + (size_t)(s * 8 + nf) * 512);
    };
    auto step = [&](int s) {
        const char* la = (const char*)&Atile[s % 3][0];
        const bf16x8* bf = breg[s % 3];
        #pragma unroll
        for (int mf = 0; mf < 4; ++mf) {
            int rb = (wr * 64 + mf * 16 + lm) * 128;
            f32x4 f0 = *reinterpret_cast<const f32x4*>(la + rb + koff0);
            f32x4 f1 = *reinterpret_cast<const f32x4*>(la + rb + (koff0 ^ 16));
            bf16x8 af = cvt8(f0, f1);
            #pragma unroll
            for (int nf = 0; nf < 4; ++nf)
                acc[mf][nf] = __builtin_amdgcn_mfma_f32_16x16x32_bf16(
                    af, bf[nf], acc[mf][nf], 0, 0, 0);
        }
    };

    prefetchA(0, 0); loadB(0, breg[0]);
    prefetchA(1, 1); loadB(1, breg[1]);

    #pragma unroll
    for (int s = 0; s < 4; ++s) {
        if (s == 3) { asm volatile("s_waitcnt vmcnt(0)" ::: "memory"); }
        else        { asm volatile("s_waitcnt vmcnt(8)" ::: "memory"); }
        __builtin_amdgcn_s_barrier();
        asm volatile("" ::: "memory");
        if (s < 2) { prefetchA(s + 2, (s + 2) % 3); loadB(s + 2, breg[(s + 2) % 3]); }
        step(s);
    }

    // epilogue: bf16 partials in gather-friendly layout
    #pragma unroll
    for (int mf = 0; mf < 4; ++mf) {
        #pragma unroll
        for (int j = 0; j < 4; ++j) {
            int row = r0 + wr * 64 + mf * 16 + lk * 4 + j;
            if (row < M) {
                u16x4 v;
                #pragma unroll
                for (int nf = 0; nf < 4; ++nf)
                    v[nf] = f2bf_s(acc[mf][nf][j]);
                *reinterpret_cast<u16x4*>(P2 + (size_t)row * 128 + wc * 64 + lm * 4) = v;
            }
        }
    }
}

// ---------------- main: out = relu(rev @ Wr + U2[u] + I2[i]) ----------------
// Pure-streaming A (review rows), K=128 in 4 steps; epilogue adds gathered
// bf16 partials (256B/review/table instead of R7's 512B f32 in-loop gathers).
__global__ __launch_bounds__(256, 3) void agg_kernel(
    const float* __restrict__ rev,
    const int*   __restrict__ uidx,
    const int*   __restrict__ iidx,
    const unsigned short* __restrict__ ws,
    float* __restrict__ out)
{
    __shared__ __align__(16) float Atile[3][128 * 32];

    const int r0   = blockIdx.x * 128;
    const int t    = threadIdx.x;
    const int wid  = t >> 6, lane = t & 63;
    const int wr   = wid >> 1, wc = wid & 1;
    const int lm   = lane & 15, lk = lane >> 4;

    const int srow = t >> 3;
    const int cswz = ((t & 7) ^ ((t >> 3) & 7)) << 2;

    const float* pr[4];
    #pragma unroll
    for (int it = 0; it < 4; ++it) {
        int gr = r0 + it * 32 + srow;
        if (gr >= NREV) gr = NREV - 1;
        pr[it] = rev + (size_t)gr * DIM + cswz;
    }

    f32x4 acc[4][4];
    #pragma unroll
    for (int i = 0; i < 4; ++i)
        #pragma unroll
        for (int j = 0; j < 4; ++j)
            acc[i][j] = (f32x4){0.f, 0.f, 0.f, 0.f};

    const int axor  = (lm & 7) << 4;
    const int koff0 = (lk * 32) ^ axor;
    const unsigned short* bbase = ws + WR_OFF + ((wc * 4) * 64 + lane) * 8;
    const unsigned short* U2 = ws + U2_OFF;
    const unsigned short* I2 = ws + I2_OFF;

    auto prefetchA = [&](int s, int buf) {
        const int cb = s * 32;
        #pragma unroll
        for (int it = 0; it < 4; ++it)
            gload_lds16(pr[it] + cb, (char*)&Atile[buf][0] + it * 4096 + t * 16);
    };
    bf16x8 breg[3][4];
    auto loadB = [&](int s, bf16x8* dst) {
        #pragma unroll
        for (int nf = 0; nf < 4; ++nf)
            dst[nf] = *reinterpret_cast<const bf16x8*>(bbase + (size_t)(s * 8 + nf) * 512);
    };
    auto step = [&](int s) {
        const char* la = (const char*)&Atile[s % 3][0];
        const bf16x8* bf = breg[s % 3];
        #pragma unroll
        for (int mf = 0; mf < 4; ++mf) {
            int rb = (wr * 64 + mf * 16 + lm) * 128;
            f32x4 f0 = *reinterpret_cast<const f32x4*>(la + rb + koff0);
            f32x4 f1 = *reinterpret_cast<const f32x4*>(la + rb + (koff0 ^ 16));
            bf16x8 af = cvt8(f0, f1);
            #pragma unroll
            for (int nf = 0; nf < 4; ++nf)
                acc[mf][nf] = __builtin_amdgcn_mfma_f32_16x16x32_bf16(
                    af, bf[nf], acc[mf][nf], 0, 0, 0);
        }
    };

    prefetchA(0, 0); loadB(0, breg[0]);
    prefetchA(1, 1); loadB(1, breg[1]);

    #pragma unroll
    for (int s = 0; s < 4; ++s) {
        if (s == 3) { asm volatile("s_waitcnt vmcnt(0)" ::: "memory"); }
        else        { asm volatile("s_waitcnt vmcnt(8)" ::: "memory"); }
        __builtin_amdgcn_s_barrier();
        asm volatile("" ::: "memory");
        if (s < 2) { prefetchA(s + 2, (s + 2) % 3); loadB(s + 2, breg[(s + 2) % 3]); }
        step(s);
    }

    // epilogue: gather bf16 partials, add, ReLU, store
    #pragma unroll
    for (int mf = 0; mf < 4; ++mf) {
        #pragma unroll
        for (int j = 0; j < 4; ++j) {
            int row = r0 + wr * 64 + mf * 16 + lk * 4 + j;
            if (row < NREV) {
                int u = uidx[row], i = iidx[row];
                u16x4 gu = *reinterpret_cast<const u16x4*>(
                    U2 + (size_t)u * 128 + wc * 64 + lm * 4);
                u16x4 gi = *reinterpret_cast<const u16x4*>(
                    I2 + (size_t)i * 128 + wc * 64 + lm * 4);
                float* orow = out + (size_t)row * DIM + wc * 64;
                #pragma unroll
                for (int nf = 0; nf < 4; ++nf)
                    orow[nf * 16 + lm] =
                        fmaxf(acc[mf][nf][j] + bf2f(gu[nf]) + bf2f(gi[nf]), 0.0f);
            }
        }
    }
}

extern "C" void kernel_launch(void* const* d_in, const int* in_sizes, int n_in,
                              void* d_out, int out_size, void* d_ws, size_t ws_size,
                              hipStream_t stream) {
    const float* rev  = (const float*)d_in[0];
    const float* item = (const float*)d_in[1];
    const float* user = (const float*)d_in[2];
    const int*   uidx = (const int*)d_in[3];
    const int*   iidx = (const int*)d_in[4];
    const float* W    = (const float*)d_in[5];
    unsigned short* ws = (unsigned short*)d_ws;   // needs ~77 MB
    float* out = (float*)d_out;

    wconv_kernel<<<192, 256, 0, stream>>>(W, ws);
    precomp_kernel<<<UBLK + IBLK, 256, 0, stream>>>(user, item, ws);

    int nblocks = (NREV + 127) / 128;   // 3907
    agg_kernel<<<nblocks, 256, 0, stream>>>(rev, uidx, iidx, ws, out);
}

// Round 9
// 184.388 us; speedup vs baseline: 1.2587x; 1.1990x over previous
//
#include <hip/hip_runtime.h>
#include <hip/hip_bf16.h>

#define NREV  500000
#define NUSER 200000
#define NITEM 100000
#define DIM   128

// d_ws layout in ushort (bf16) elements:
#define WR_OFF 0                         // rev-part weight frag, 16384
#define WU_OFF 16384                     // user-part weight frag
#define WI_OFF 32768                     // item-part weight frag
#define U2_OFF 49152                     // user partial products, 200000*128
#define I2_OFF (49152 + NUSER * 128)     // item partial products, 100000*128
#define UBLK 1563                        // ceil(200000/128)
#define IBLK 782                         // ceil(100000/128)

typedef __attribute__((ext_vector_type(4))) float f32x4;
typedef __attribute__((ext_vector_type(8))) short bf16x8;
typedef __attribute__((ext_vector_type(4))) unsigned short u16x4;

__device__ __forceinline__ unsigned short f2bf_s(float x) {
    // round-to-nearest-even f32 -> bf16
    unsigned int u = __builtin_bit_cast(unsigned int, x);
    u = (u + 0x7FFFu + ((u >> 16) & 1u)) >> 16;
    return (unsigned short)u;
}
__device__ __forceinline__ float bf2f(unsigned short u) {
    return __builtin_bit_cast(float, (unsigned int)u << 16);
}

// W [384][128] f32 -> three frag-linear bf16 blocks (rev/user/item K-slices).
__global__ void wconv_kernel(const float* __restrict__ W,
                             unsigned short* __restrict__ ws) {
    int e = blockIdx.x * 256 + threadIdx.x;
    if (e < 3 * 16384) {
        int e14 = e & 16383;
        int b  = e >> 14;
        int ks = e14 >> 12;
        int fg = (e14 >> 9) & 7;
        int l  = (e14 >> 3) & 63;
        int j  = e14 & 7;
        int n = fg * 16 + (l & 15);
        int k = b * 128 + ks * 32 + ((l >> 4) << 3) + j;
        ws[e] = f2bf_s(W[k * DIM + n]);
    }
}

__device__ __forceinline__ void gload_lds16(const void* g, void* l) {
    __builtin_amdgcn_global_load_lds(
        (const __attribute__((address_space(1))) void*)g,
        (__attribute__((address_space(3))) void*)l, 16, 0, 0);
}

// pack hi16 of two f32 into one dword of two bf16 (truncation): v_perm_b32
__device__ __forceinline__ unsigned int pk2(float lo, float hi) {
    return __builtin_amdgcn_perm(__builtin_bit_cast(unsigned int, hi),
                                 __builtin_bit_cast(unsigned int, lo),
                                 0x07060302u);
}
__device__ __forceinline__ bf16x8 cvt8(f32x4 a, f32x4 b) {
    union { bf16x8 v; unsigned int u[4]; } U;
    U.u[0] = pk2(a[0], a[1]);
    U.u[1] = pk2(a[2], a[3]);
    U.u[2] = pk2(b[0], b[1]);
    U.u[3] = pk2(b[2], b[3]);
    return U.v;
}

// ---------------- precompute: P2 = bf16(table @ Wx), streaming GEMM ----------
// (unchanged from R8 — measured ~5.8 TB/s)
__global__ __launch_bounds__(256, 3) void precomp_kernel(
    const float* __restrict__ user,
    const float* __restrict__ item,
    unsigned short* __restrict__ ws)
{
    __shared__ __align__(16) float Atile[3][128 * 32];

    const bool isU = blockIdx.x < UBLK;
    const float* tab = isU ? user : item;
    const int M      = isU ? NUSER : NITEM;
    const unsigned short* wf = ws + (isU ? WU_OFF : WI_OFF);
    unsigned short* P2       = ws + (isU ? U2_OFF : I2_OFF);
    const int r0 = (isU ? blockIdx.x : blockIdx.x - UBLK) * 128;

    const int t    = threadIdx.x;
    const int wid  = t >> 6, lane = t & 63;
    const int wr   = wid >> 1, wc = wid & 1;
    const int lm   = lane & 15, lk = lane >> 4;

    const int srow = t >> 3;
    const int cswz = ((t & 7) ^ ((t >> 3) & 7)) << 2;

    const float* pr[4];
    #pragma unroll
    for (int it = 0; it < 4; ++it) {
        int gr = r0 + it * 32 + srow;
        if (gr >= M) gr = M - 1;
        pr[it] = tab + (size_t)gr * DIM + cswz;
    }

    f32x4 acc[4][4];
    #pragma unroll
    for (int i = 0; i < 4; ++i)
        #pragma unroll
        for (int j = 0; j < 4; ++j)
            acc[i][j] = (f32x4){0.f, 0.f, 0.f, 0.f};

    const int axor  = (lm & 7) << 4;
    const int koff0 = (lk * 32) ^ axor;
    const unsigned short* bbase = wf + ((wc * 4) * 64 + lane) * 8;

    auto prefetchA = [&](int s, int buf) {
        const int cb = s * 32;
        #pragma unroll
        for (int it = 0; it < 4; ++it)
            gload_lds16(pr[it] + cb, (char*)&Atile[buf][0] + it * 4096 + t * 16);
    };
    bf16x8 breg[3][4];
    auto loadB = [&](int s, bf16x8* dst) {
        #pragma unroll
        for (int nf = 0; nf < 4; ++nf)
            dst[nf] = *reinterpret_cast<const bf16x8*>(bbase + (size_t)(s * 8 + nf) * 512);
    };
    auto step = [&](int s) {
        const char* la = (const char*)&Atile[s % 3][0];
        const bf16x8* bf = breg[s % 3];
        #pragma unroll
        for (int mf = 0; mf < 4; ++mf) {
            int rb = (wr * 64 + mf * 16 + lm) * 128;
            f32x4 f0 = *reinterpret_cast<const f32x4*>(la + rb + koff0);
            f32x4 f1 = *reinterpret_cast<const f32x4*>(la + rb + (koff0 ^ 16));
            bf16x8 af = cvt8(f0, f1);
            #pragma unroll
            for (int nf = 0; nf < 4; ++nf)
                acc[mf][nf] = __builtin_amdgcn_mfma_f32_16x16x32_bf16(
                    af, bf[nf], acc[mf][nf], 0, 0, 0);
        }
    };

    prefetchA(0, 0); loadB(0, breg[0]);
    prefetchA(1, 1); loadB(1, breg[1]);

    #pragma unroll
    for (int s = 0; s < 4; ++s) {
        if (s == 3) { asm volatile("s_waitcnt vmcnt(0)" ::: "memory"); }
        else        { asm volatile("s_waitcnt vmcnt(8)" ::: "memory"); }
        __builtin_amdgcn_s_barrier();
        asm volatile("" ::: "memory");
        if (s < 2) { prefetchA(s + 2, (s + 2) % 3); loadB(s + 2, breg[(s + 2) % 3]); }
        step(s);
    }

    // epilogue: bf16 partials in gather-friendly layout
    #pragma unroll
    for (int mf = 0; mf < 4; ++mf) {
        #pragma unroll
        for (int j = 0; j < 4; ++j) {
            int row = r0 + wr * 64 + mf * 16 + lk * 4 + j;
            if (row < M) {
                u16x4 v;
                #pragma unroll
                for (int nf = 0; nf < 4; ++nf)
                    v[nf] = f2bf_s(acc[mf][nf][j]);
                *reinterpret_cast<u16x4*>(P2 + (size_t)row * 128 + wc * 64 + lm * 4) = v;
            }
        }
    }
}

// ---------------- main: out = relu(rev @ Wr + U2[u] + I2[i]) ----------------
// R9: epilogue gathers go WIDE (all 32 at once into static-indexed register
// arrays, 256-VGPR budget) with indices staged in LDS (lgkm path, doesn't
// disturb the loop's vmcnt discipline). One L3-latency tail instead of many.
__global__ __launch_bounds__(256, 2) void agg_kernel(
    const float* __restrict__ rev,
    const int*   __restrict__ uidx,
    const int*   __restrict__ iidx,
    const unsigned short* __restrict__ ws,
    float* __restrict__ out)
{
    __shared__ __align__(16) float Atile[3][128 * 32];
    __shared__ int su[128];
    __shared__ int si[128];

    const int r0   = blockIdx.x * 128;
    const int t    = threadIdx.x;
    const int wid  = t >> 6, lane = t & 63;
    const int wr   = wid >> 1, wc = wid & 1;
    const int lm   = lane & 15, lk = lane >> 4;

    // stage gather indices once (consumed after the loop's barriers)
    if (t < 128) {
        int gr = r0 + t;
        if (gr >= NREV) gr = NREV - 1;
        su[t] = uidx[gr];
        si[t] = iidx[gr];
    }

    const int srow = t >> 3;
    const int cswz = ((t & 7) ^ ((t >> 3) & 7)) << 2;

    const float* pr[4];
    #pragma unroll
    for (int it = 0; it < 4; ++it) {
        int gr = r0 + it * 32 + srow;
        if (gr >= NREV) gr = NREV - 1;
        pr[it] = rev + (size_t)gr * DIM + cswz;
    }

    f32x4 acc[4][4];
    #pragma unroll
    for (int i = 0; i < 4; ++i)
        #pragma unroll
        for (int j = 0; j < 4; ++j)
            acc[i][j] = (f32x4){0.f, 0.f, 0.f, 0.f};

    const int axor  = (lm & 7) << 4;
    const int koff0 = (lk * 32) ^ axor;
    const unsigned short* bbase = ws + WR_OFF + ((wc * 4) * 64 + lane) * 8;
    const unsigned short* U2 = ws + U2_OFF;
    const unsigned short* I2 = ws + I2_OFF;

    auto prefetchA = [&](int s, int buf) {
        const int cb = s * 32;
        #pragma unroll
        for (int it = 0; it < 4; ++it)
            gload_lds16(pr[it] + cb, (char*)&Atile[buf][0] + it * 4096 + t * 16);
    };
    bf16x8 breg[3][4];
    auto loadB = [&](int s, bf16x8* dst) {
        #pragma unroll
        for (int nf = 0; nf < 4; ++nf)
            dst[nf] = *reinterpret_cast<const bf16x8*>(bbase + (size_t)(s * 8 + nf) * 512);
    };
    auto step = [&](int s) {
        const char* la = (const char*)&Atile[s % 3][0];
        const bf16x8* bf = breg[s % 3];
        #pragma unroll
        for (int mf = 0; mf < 4; ++mf) {
            int rb = (wr * 64 + mf * 16 + lm) * 128;
            f32x4 f0 = *reinterpret_cast<const f32x4*>(la + rb + koff0);
            f32x4 f1 = *reinterpret_cast<const f32x4*>(la + rb + (koff0 ^ 16));
            bf16x8 af = cvt8(f0, f1);
            #pragma unroll
            for (int nf = 0; nf < 4; ++nf)
                acc[mf][nf] = __builtin_amdgcn_mfma_f32_16x16x32_bf16(
                    af, bf[nf], acc[mf][nf], 0, 0, 0);
        }
    };

    prefetchA(0, 0); loadB(0, breg[0]);
    prefetchA(1, 1); loadB(1, breg[1]);

    #pragma unroll
    for (int s = 0; s < 4; ++s) {
        if (s == 3) { asm volatile("s_waitcnt vmcnt(0)" ::: "memory"); }
        else        { asm volatile("s_waitcnt vmcnt(8)" ::: "memory"); }
        __builtin_amdgcn_s_barrier();
        asm volatile("" ::: "memory");
        if (s < 2) { prefetchA(s + 2, (s + 2) % 3); loadB(s + 2, breg[(s + 2) % 3]); }
        step(s);
    }

    // ---- epilogue phase 1: issue ALL partial-product gathers, wide.
    // Row of (mf,j): local = wr*64 + mf*16 + lk*4 + j. Indices from LDS
    // (lgkmcnt path). 32 x 8B gathers live at once = 64 VGPRs.
    u16x4 gu[4][4], gi[4][4];
    #pragma unroll
    for (int mf = 0; mf < 4; ++mf) {
        #pragma unroll
        for (int j = 0; j < 4; ++j) {
            int rl = wr * 64 + mf * 16 + lk * 4 + j;
            int u = su[rl], i = si[rl];
            gu[mf][j] = *reinterpret_cast<const u16x4*>(
                U2 + (size_t)u * 128 + wc * 64 + lm * 4);
            gi[mf][j] = *reinterpret_cast<const u16x4*>(
                I2 + (size_t)i * 128 + wc * 64 + lm * 4);
        }
    }
    asm volatile("" ::: "memory");   // keep all gathers issued before combines

    // ---- epilogue phase 2: combine + ReLU + store
    #pragma unroll
    for (int mf = 0; mf < 4; ++mf) {
        #pragma unroll
        for (int j = 0; j < 4; ++j) {
            int row = r0 + wr * 64 + mf * 16 + lk * 4 + j;
            if (row < NREV) {
                float* orow = out + (size_t)row * DIM + wc * 64;
                #pragma unroll
                for (int nf = 0; nf < 4; ++nf)
                    orow[nf * 16 + lm] =
                        fmaxf(acc[mf][nf][j] + bf2f(gu[mf][j][nf]) + bf2f(gi[mf][j][nf]), 0.0f);
            }
        }
    }
}

extern "C" void kernel_launch(void* const* d_in, const int* in_sizes, int n_in,
                              void* d_out, int out_size, void* d_ws, size_t ws_size,
                              hipStream_t stream) {
    const float* rev  = (const float*)d_in[0];
    const float* item = (const float*)d_in[1];
    const float* user = (const float*)d_in[2];
    const int*   uidx = (const int*)d_in[3];
    const int*   iidx = (const int*)d_in[4];
    const float* W    = (const float*)d_in[5];
    unsigned short* ws = (unsigned short*)d_ws;   // needs ~77 MB
    float* out = (float*)d_out;

    wconv_kernel<<<192, 256, 0, stream>>>(W, ws);
    precomp_kernel<<<UBLK + IBLK, 256, 0, stream>>>(user, item, ws);

    int nblocks = (NREV + 127) / 128;   // 3907
    agg_kernel<<<nblocks, 256, 0, stream>>>(rev, uidx, iidx, ws, out);
}